// Round 5
// baseline (26967.331 us; speedup 1.0000x reference)
//
#include <hip/hip_runtime.h>

// ConditionalSmilesRnn: 3-layer LSTM, B=256, H=1024, steps=99, V=47, P=3.
// R5: PERSISTENT kernel. Weights (40 MB) live in LDS (exactly 160 KB/CU x 256 CUs),
// loaded once; 104 diagonal steps run inside one kernel with atomic grid barriers.
// Layers split into x-GEMM / h-GEMM -> 5 uniform GEMMs [256x4096x1024] = 20480
// cols = 256 WGs x 80 cols (16-col gate-interleaved chunks). Phase A: MFMA from
// LDS weights, h streamed from L2 (2-deep reg prefetch). Phase B: fused cells
// (coalesced [n'][m] f32 gates) + per-WG decoder row (Wdec in registers) -> d_out.

typedef unsigned short u16;
typedef __bf16 bf16x8 __attribute__((ext_vector_type(8)));
typedef float f32x4 __attribute__((ext_vector_type(4)));
typedef u16 u16x8 __attribute__((ext_vector_type(8)));

#define MFMA16(a,b,c) __builtin_amdgcn_mfma_f32_16x16x32_bf16((a),(b),(c),0,0,0)

__device__ __forceinline__ u16 f2bf(float f){
  unsigned u = __builtin_bit_cast(unsigned, f);
  u += 0x7fffu + ((u >> 16) & 1u);          // RN-even
  return (u16)(u >> 16);
}
__device__ __forceinline__ float bf2f(u16 s){
  unsigned u = ((unsigned)s) << 16;
  return __builtin_bit_cast(float, u);
}
__device__ __forceinline__ float sigm(float x){ return 1.f/(1.f+__expf(-x)); }
__device__ __forceinline__ float tanhfast(float x){ return 1.f - 2.f/(__expf(2.f*x)+1.f); }

__device__ __forceinline__ void ld_lds16(const u16* g, u16* l){
  __builtin_amdgcn_global_load_lds((const __attribute__((address_space(1))) void*)g,
                                   (__attribute__((address_space(3))) void*)l, 16, 0, 0);
}

// ---- f32 -> bf16 strided converter
__global__ void k_conv(const float* __restrict__ src, u16* __restrict__ dst,
                       long total, int srow, int sstride, int dstride, int doff){
  long i = ((long)blockIdx.x*blockDim.x + threadIdx.x)*8;
  if (i >= total) return;
  long r = i / srow;
  int  k = (int)(i - r*srow);
  const float* s = src + r*(long)sstride + k;
  u16x8 o;
  #pragma unroll
  for (int j=0;j<8;++j) o[j] = f2bf(s[j]);
  *(u16x8*)(dst + r*(long)dstride + doff + k) = o;
}

// ---- weight pack for the persistent kernel.
// piece p = (wgc<<11) + (ks<<6) + lane ; 16B piece = A-frag slice:
//   n'(col) = wgc*16 + (lane&15), k = ks*32 + (lane>>4)*8 + j
// gemm g = n'>>12 in {Whh0, Wih1, Whh1, Wih2, Whh2}; within-gemm col nc = n'&4095
// source row n = ((nc>>4)&3)*1024 + (nc>>6)*16 + (nc&15)   (gate-interleave)
__global__ void k_pack(const float* __restrict__ Whh0, const float* __restrict__ Wih_r,
                       const float* __restrict__ Whh_r, u16* __restrict__ Wpk){
  int b = blockIdx.x;                        // 10240 blocks
  int wgc = b >> 3;
  int np2 = (b & 7)*2 + (threadIdx.x >> 7);  // lane&15  (0..15)
  int ko  = (threadIdx.x & 127)*8;           // k offset (0..1016)
  int np  = wgc*16 + np2;                    // absolute col
  int g = np >> 12, nc = np & 4095;
  int n = ((nc>>4)&3)*1024 + ((nc>>6)<<4) + (nc&15);
  const float* s;
  if      (g==0) s = Whh0;
  else if (g==1) s = Wih_r;
  else if (g==2) s = Whh_r;
  else if (g==3) s = Wih_r + (size_t)4096*1024;
  else           s = Whh_r + (size_t)4096*1024;
  s += (size_t)n*1024 + ko;
  int ks = ko >> 5, l4 = (ko >> 3) & 3;
  long p = ((long)wgc << 11) + (ks << 6) + ((l4 << 4) | np2);
  u16x8 o;
  #pragma unroll
  for (int j=0;j<8;++j) o[j] = f2bf(s[j]);
  *(u16x8*)(Wpk + p*8) = o;
}

// ---- misc prep: biases, pad rows, state init, gxpT(+bias0), barrier zero
__global__ void k_misc(const float* __restrict__ b_ih0, const float* __restrict__ b_hh0,
                       const float* __restrict__ b_ihr, const float* __restrict__ b_hhr,
                       const float* __restrict__ h0, const float* __restrict__ c0,
                       const float* __restrict__ props, const float* __restrict__ W_ih0,
                       u16* __restrict__ Ebf, u16* __restrict__ Wdecb,
                       float* __restrict__ bcat, u16* __restrict__ hb,
                       float* __restrict__ cT, float* __restrict__ gxpT,
                       unsigned* __restrict__ bars){
  long i = (long)blockIdx.x*256 + threadIdx.x;
  if (i < 8192){ bcat[i] = b_ihr[i] + b_hhr[i]; return; }
  i -= 8192;
  if (i < 1024){ Ebf[48128 + i] = 0; Wdecb[48128 + i] = 0; return; }
  i -= 1024;
  if (i < 786432){            // h init -> parity-1 buffers
    int l = (int)(i >> 18); long r = i & 262143;
    hb[((size_t)l*2 + 1)*262144 + r] = f2bf(h0[i]);
    return;
  }
  i -= 786432;
  if (i < 786432){            // c init, transposed [l][hcol][m]
    int l = (int)(i >> 18); long r = i & 262143;
    int m = (int)(r >> 10), hc = (int)(r & 1023);
    cT[(size_t)l*262144 + (size_t)hc*256 + m] = c0[i];
    return;
  }
  i -= 786432;
  if (i < 1048576){           // gxpT[n][m] = props proj + b_ih0 + b_hh0
    int n = (int)(i >> 8), m = (int)(i & 255);
    const float* wr = W_ih0 + (long)n*1027 + 1024;
    gxpT[i] = props[m*3+0]*wr[0] + props[m*3+1]*wr[1] + props[m*3+2]*wr[2]
            + b_ih0[n] + b_hh0[n];
    return;
  }
  i -= 1048576;
  if (i < 256) bars[i] = 0;
}

// ---- gx_emb[v][n] = sum_k E[v][k] * W_ih0[n][k]  (original n order)
__global__ __launch_bounds__(64)
void k_gxemb(const u16* __restrict__ Ebf, const u16* __restrict__ Wih0b, float* __restrict__ gxe){
  const int lane = threadIdx.x;
  const int cl = lane & 15, ko = (lane >> 4)*8;
  const int m0 = blockIdx.x*16;
  const int n0 = blockIdx.y*16;
  f32x4 acc = {0.f,0.f,0.f,0.f};
  const u16* ap = Ebf   + (size_t)(m0+cl)*1024 + ko;
  const u16* bp = Wih0b + (size_t)(n0+cl)*1024 + ko;
  for (int k0=0; k0<1024; k0+=32){
    bf16x8 a = *(const bf16x8*)(ap + k0);
    bf16x8 b = *(const bf16x8*)(bp + k0);
    acc = MFMA16(a, b, acc);
  }
  const int rbase = (lane >> 4)*4;
  #pragma unroll
  for (int q=0;q<4;++q){
    int v = m0 + rbase + q;
    if (v < 47) gxe[(size_t)v*4096 + n0 + cl] = acc[q];
  }
}

// ---- grid barrier (one-shot counter per instance; zeroed in prep each launch)
__device__ __forceinline__ void gbar(unsigned* ctr){
  __threadfence();
  __syncthreads();
  if (threadIdx.x == 0){
    __hip_atomic_fetch_add(ctr, 1u, __ATOMIC_RELAXED, __HIP_MEMORY_SCOPE_AGENT);
    while (__hip_atomic_load(ctr, __ATOMIC_RELAXED, __HIP_MEMORY_SCOPE_AGENT) < 256u)
      __builtin_amdgcn_s_sleep(1);
  }
  __syncthreads();
  __threadfence();
}

// ---- phase-A K loop: 5 chunks, chunks [0,NS) use F input, [NS,5) use L input.
template<int NS>
__device__ __forceinline__ void kloop(const u16* lds, int lane,
    const u16* paF0, const u16* paF1, const u16* paL0, const u16* paL1,
    f32x4 (&acc)[5][2])
{
  const u16* lp = lds + lane*8;
  bf16x8 cF0 = *(const bf16x8*)(paF0),      cF1 = *(const bf16x8*)(paF1);
  bf16x8 dF0 = *(const bf16x8*)(paF0 + 32), dF1 = *(const bf16x8*)(paF1 + 32);
  bf16x8 cL0{}, cL1{}, dL0{}, dL1{};
  if (NS < 5){
    cL0 = *(const bf16x8*)(paL0);      cL1 = *(const bf16x8*)(paL1);
    dL0 = *(const bf16x8*)(paL0 + 32); dL1 = *(const bf16x8*)(paL1 + 32);
  }
  #pragma unroll 1
  for (int ks=0; ks<32; ks+=2){
    int k2 = ((ks+2)&31)*32;
    bf16x8 eF0 = *(const bf16x8*)(paF0 + k2), eF1 = *(const bf16x8*)(paF1 + k2);
    bf16x8 eL0{}, eL1{};
    if (NS<5){ eL0 = *(const bf16x8*)(paL0 + k2); eL1 = *(const bf16x8*)(paL1 + k2); }
    {
      bf16x8 a0 = *(const bf16x8*)(lp + (0*32+ks)*512);
      bf16x8 a1 = *(const bf16x8*)(lp + (1*32+ks)*512);
      bf16x8 a2 = *(const bf16x8*)(lp + (2*32+ks)*512);
      bf16x8 a3 = *(const bf16x8*)(lp + (3*32+ks)*512);
      bf16x8 a4 = *(const bf16x8*)(lp + (4*32+ks)*512);
      #define CH(c,A) { bf16x8 u0=(c<NS)?cF0:cL0, u1=(c<NS)?cF1:cL1; \
        acc[c][0]=MFMA16(A,u0,acc[c][0]); acc[c][1]=MFMA16(A,u1,acc[c][1]); }
      CH(0,a0) CH(1,a1) CH(2,a2) CH(3,a3) CH(4,a4)
      #undef CH
    }
    int k3 = ((ks+3)&31)*32;
    bf16x8 fF0 = *(const bf16x8*)(paF0 + k3), fF1 = *(const bf16x8*)(paF1 + k3);
    bf16x8 fL0{}, fL1{};
    if (NS<5){ fL0 = *(const bf16x8*)(paL0 + k3); fL1 = *(const bf16x8*)(paL1 + k3); }
    {
      int ks1 = ks+1;
      bf16x8 a0 = *(const bf16x8*)(lp + (0*32+ks1)*512);
      bf16x8 a1 = *(const bf16x8*)(lp + (1*32+ks1)*512);
      bf16x8 a2 = *(const bf16x8*)(lp + (2*32+ks1)*512);
      bf16x8 a3 = *(const bf16x8*)(lp + (3*32+ks1)*512);
      bf16x8 a4 = *(const bf16x8*)(lp + (4*32+ks1)*512);
      #define CH(c,A) { bf16x8 u0=(c<NS)?dF0:dL0, u1=(c<NS)?dF1:dL1; \
        acc[c][0]=MFMA16(A,u0,acc[c][0]); acc[c][1]=MFMA16(A,u1,acc[c][1]); }
      CH(0,a0) CH(1,a1) CH(2,a2) CH(3,a3) CH(4,a4)
      #undef CH
    }
    cF0=eF0; cF1=eF1; dF0=fF0; dF1=fF1;
    if (NS<5){ cL0=eL0; cL1=eL1; dL0=fL0; dL1=fL1; }
  }
}

// ---- the persistent kernel
__global__ __launch_bounds__(512, 2)
void k_lstm(const int* __restrict__ x, const u16* __restrict__ Wpk,
            const float* __restrict__ gxe, const float* __restrict__ gxpT,
            const float* __restrict__ bcat, const u16* __restrict__ Wdecb,
            const float* __restrict__ bdec,
            u16* __restrict__ hb, float* __restrict__ cT,
            float* __restrict__ G0, float* __restrict__ G2, float* __restrict__ G4,
            float* __restrict__ pre1, float* __restrict__ pre2,
            float* __restrict__ logits, unsigned* __restrict__ bars)
{
  extern __shared__ u16 lds[];
  const int wg = blockIdx.x, tid = threadIdx.x;
  const int lane = tid & 63, wv = tid >> 6;
  const int cl15 = lane & 15, k8 = (lane >> 4)*8;
  const int m0 = wv*32;

  // stage this WG's 160 KB weight slice into LDS (once)
  #pragma unroll
  for (int it=0; it<20; ++it){
    int gsl = it*512 + tid;
    ld_lds16(Wpk + (size_t)wg*81920 + (size_t)gsl*8, lds + (size_t)gsl*8);
  }
  asm volatile("s_waitcnt vmcnt(0)" ::: "memory");
  __syncthreads();

  // decoder weights for this WG's m-row (wv<6): v = wv*8+(lane>>3), k-slice 128
  bf16x8 wd[16];
  {
    int v = (wv<6) ? wv*8 + (lane>>3) : 0;
    int kb = (lane & 7)*128;
    const u16* wp = Wdecb + (size_t)v*1024 + kb;
    #pragma unroll
    for (int j=0;j<16;++j) wd[j] = *(const bf16x8*)(wp + j*8);
  }

  // geometry (constant per WG)
  const int col0 = wg*80;
  const int gcF = col0 >> 12;
  const int gcL = (col0 + 64) >> 12;
  const int nsplit = (gcF==gcL) ? 5 : ((((gcF+1)<<12) - col0) >> 4);
  const int linF = gcF >> 1, linL = gcL >> 1;    // input layer: {0,0,1,1,2}
  const bool preF = (gcF==1) | (gcF==3);
  const bool preL = (gcL==1) | (gcL==3);
  float* const baseTab0 = G0;  // gemm->buffer: {G0, pre1, G2, pre2, G4}
  float* baseF = (gcF==0)?G0:(gcF==1)?pre1:(gcF==2)?G2:(gcF==3)?pre2:G4;
  float* baseL = (gcL==0)?G0:(gcL==1)?pre1:(gcL==2)?G2:(gcL==3)?pre2:G4;
  (void)baseTab0;

  for (int d=0; d<104; ++d){
    // ---------------- phase A: GEMMs ----------------
    const int q = (d+1)&1;                       // input parity == (d-1)&1
    const bool okF = (unsigned)(d - gcF) <= 98u;
    const bool okL = (unsigned)(d - gcL) <= 98u;
    if (okF | okL){
      const u16* inF = hb + ((size_t)linF*2 + q)*262144;
      const u16* inL = hb + ((size_t)linL*2 + q)*262144;
      const u16* paF0 = inF + (size_t)(m0+cl15)*1024 + k8;
      const u16* paF1 = paF0 + 16*1024;
      const u16* paL0 = inL + (size_t)(m0+cl15)*1024 + k8;
      const u16* paL1 = paL0 + 16*1024;
      f32x4 acc[5][2];
      #pragma unroll
      for (int c=0;c<5;++c){ acc[c][0]=(f32x4){0,0,0,0}; acc[c][1]=(f32x4){0,0,0,0}; }
      switch (nsplit){
        case 5: kloop<5>(lds, lane, paF0, paF1, paF0, paF1, acc); break;
        case 1: kloop<1>(lds, lane, paF0, paF1, paL0, paL1, acc); break;
        case 2: kloop<2>(lds, lane, paF0, paF1, paL0, paL1, acc); break;
        case 3: kloop<3>(lds, lane, paF0, paF1, paL0, paL1, acc); break;
        default: kloop<4>(lds, lane, paF0, paF1, paL0, paL1, acc); break;
      }
      // stores (guarded per chunk)
      float* pF = baseF + (preF ? (size_t)q*1048576 : 0);
      float* pL = baseL + (preL ? (size_t)q*1048576 : 0);
      #pragma unroll
      for (int c=0;c<5;++c){
        bool useF = c < nsplit;
        float* bp = useF ? pF : pL;
        if (useF ? okF : okL){
          int nb = ((col0 + c*16) & 4095) + ((lane>>4)<<2);
          #pragma unroll
          for (int f=0; f<2; ++f){
            int mcol = m0 + f*16 + cl15;
            #pragma unroll
            for (int qq=0; qq<4; ++qq)
              bp[(size_t)(nb+qq)*256 + mcol] = acc[c][f][qq];
          }
        }
      }
    }
    gbar(bars + 2*d);
    // ---------------- phase B: cells + decode ----------------
    #pragma unroll 1
    for (int it=0; it<6; ++it){
      int r = wg*12 + it*2 + (tid>>8);
      int m = tid & 255;
      int l = r >> 10, hc = r & 1023;
      int t = d - 2*l;
      if ((unsigned)t <= 98u){
        int nb = ((hc>>4)<<6) + (hc&15);
        const float* Gl = (l==0)?G0:((l==1)?G2:G4);
        float gi = Gl[(size_t)nb*256 + m];
        float gf = Gl[(size_t)(nb+16)*256 + m];
        float gg = Gl[(size_t)(nb+32)*256 + m];
        float go = Gl[(size_t)(nb+48)*256 + m];
        if (l==0){
          int tok = t ? x[m*100 + t] : 1;
          const float* ge = gxe + (size_t)tok*4096 + hc;
          gi += ge[0]    + gxpT[(size_t)hc*256 + m];
          gf += ge[1024] + gxpT[(size_t)(1024+hc)*256 + m];
          gg += ge[2048] + gxpT[(size_t)(2048+hc)*256 + m];
          go += ge[3072] + gxpT[(size_t)(3072+hc)*256 + m];
        } else {
          const float* pr = ((l==1)?pre1:pre2) + (size_t)(d&1)*1048576;
          const float* bc = bcat + (size_t)(l-1)*4096 + hc;
          gi += pr[(size_t)nb*256 + m]      + bc[0];
          gf += pr[(size_t)(nb+16)*256 + m] + bc[1024];
          gg += pr[(size_t)(nb+32)*256 + m] + bc[2048];
          go += pr[(size_t)(nb+48)*256 + m] + bc[3072];
        }
        float i_=sigm(gi), f_=sigm(gf), o_=sigm(go), g_=tanhfast(gg);
        size_t coff = (size_t)l*262144 + (size_t)hc*256 + m;
        float cn = f_*cT[coff] + i_*g_;
        cT[coff] = cn;
        hb[((size_t)l*2 + (d&1))*262144 + (size_t)m*1024 + hc] = f2bf(o_*tanhfast(cn));
      }
    }
    {
      int t5 = d - 5;
      if ((unsigned)t5 <= 98u && wv < 6){
        int v = wv*8 + (lane>>3), kb = (lane & 7)*128;
        const u16* hr = hb + ((size_t)4 + (t5&1))*262144 + (size_t)wg*1024 + kb;
        float s = 0.f;
        #pragma unroll
        for (int j=0;j<16;++j){
          u16x8 h8 = __builtin_bit_cast(u16x8, *(const bf16x8*)(hr + j*8));
          u16x8 w8 = __builtin_bit_cast(u16x8, wd[j]);
          #pragma unroll
          for (int e=0;e<8;++e) s += bf2f(w8[e]) * bf2f(h8[e]);
        }
        s += __shfl_xor(s, 1);
        s += __shfl_xor(s, 2);
        s += __shfl_xor(s, 4);
        if ((lane & 7)==0 && v < 47)
          logits[((size_t)wg*99 + t5)*47 + v] = s + bdec[v];
      }
    }
    gbar(bars + 2*d + 1);
  }
}

// ---- final hT / cT copy-out (h parity 0: t=98)
__global__ void k_final(const u16* __restrict__ hb, const float* __restrict__ cT,
                        float* __restrict__ out){
  long i = (long)blockIdx.x*256 + threadIdx.x;
  if (i < 786432){
    int l = (int)(i >> 18); long r = i & 262143;
    out[1191168 + i] = bf2f(hb[((size_t)l*2)*262144 + r]);
    int m = (int)(r >> 10), hc = (int)(r & 1023);
    out[1191168 + 786432 + i] = cT[(size_t)l*262144 + (size_t)hc*256 + m];
  }
}

extern "C" void kernel_launch(void* const* d_in, const int* in_sizes, int n_in,
                              void* d_out, int out_size, void* d_ws, size_t ws_size,
                              hipStream_t stream) {
  (void)in_sizes; (void)n_in; (void)out_size; (void)ws_size;
  const int*   x      = (const int*)  d_in[0];
  const float* props  = (const float*)d_in[1];
  const float* h0     = (const float*)d_in[2];
  const float* c0     = (const float*)d_in[3];
  const float* E      = (const float*)d_in[4];
  const float* W_ih0  = (const float*)d_in[5];
  const float* W_hh0  = (const float*)d_in[6];
  const float* b_ih0  = (const float*)d_in[7];
  const float* b_hh0  = (const float*)d_in[8];
  const float* W_ih_r = (const float*)d_in[9];
  const float* W_hh_r = (const float*)d_in[10];
  const float* b_ih_r = (const float*)d_in[11];
  const float* b_hh_r = (const float*)d_in[12];
  const float* W_dec  = (const float*)d_in[13];
  const float* b_dec  = (const float*)d_in[14];
  float* out = (float*)d_out;

  // workspace layout (~91 MB)
  u16* Wpk   = (u16*)d_ws;                      // 20,971,520 u16 (packed weights)
  u16* Ebf   = Wpk   + (size_t)20971520;        // 48*1024
  u16* Wdecb = Ebf   + 49152;                   // 48*1024 (row 47 = 0)
  u16* Wih0b = Wdecb + 49152;                   // 4096*1024 (first 1024 cols W_ih0)
  u16* hb    = Wih0b + (size_t)4194304;         // [3][2][256*1024] bf16
  float* gxe   = (float*)(hb + (size_t)1572864);// 48*4096
  float* gxpT  = gxe   + 196608;                // [4096][256] (+bias0 folded)
  float* bcat  = gxpT  + 1048576;               // 2*4096
  float* cT    = bcat  + 8192;                  // [3][1024][256]
  float* G0    = cT    + 786432;                // [4096][256]
  float* G2    = G0    + 1048576;
  float* G4    = G2    + 1048576;
  float* pre1  = G4    + 1048576;               // [2][4096][256]
  float* pre2  = pre1  + 2097152;               // [2][4096][256]
  unsigned* bars = (unsigned*)(pre2 + 2097152); // 256

  // ---- prep
  k_pack<<<10240, 256, 0, stream>>>(W_hh0, W_ih_r, W_hh_r, Wpk);
  k_conv<<<2048, 256, 0, stream>>>(W_ih0, Wih0b, (long)4096*1024, 1024, 1027, 1024, 0);
  k_conv<<<24,   256, 0, stream>>>(E,     Ebf,   (long)47*1024,   1024, 1024, 1024, 0);
  k_conv<<<24,   256, 0, stream>>>(W_dec, Wdecb, (long)47*1024,   1024, 1024, 1024, 0);
  k_misc<<<10277, 256, 0, stream>>>(b_ih0, b_hh0, b_ih_r, b_hh_r, h0, c0, props, W_ih0,
                                    Ebf, Wdecb, bcat, hb, cT, gxpT, bars);
  k_gxemb<<<dim3(3,256), 64, 0, stream>>>(Ebf, Wih0b, gxe);

  // ---- persistent recurrence (1 WG/CU, 160 KB LDS each, atomic grid barriers)
  hipFuncSetAttribute(reinterpret_cast<const void*>(k_lstm),
                      hipFuncAttributeMaxDynamicSharedMemorySize, 163840);
  k_lstm<<<256, 512, 163840, stream>>>(x, Wpk, gxe, gxpT, bcat, Wdecb, b_dec,
                                       hb, cT, G0, G2, G4, pre1, pre2, out, bars);

  // ---- final states
  k_final<<<3072, 256, 0, stream>>>(hb, cT, out);
}

// Round 6
// 3869.101 us; speedup vs baseline: 6.9699x; 6.9699x over previous
//
#include <hip/hip_runtime.h>

// ConditionalSmilesRnn: 3-layer LSTM, B=256, H=1024, steps=99, V=47, P=3.
// R6: R3 structure (diag-fused dispatches, LDS staging, gate-interleaved
// weights) + (1) weights repacked into per-(layer,jt) CONTIGUOUS stream blocks
// in exact staging-granule order (swizzle baked in), (2) 3-slot LDS pipeline,
// 2-deep prefetch, ONE barrier per K-chunk, counted vmcnt, (3) setprio around
// the compute cluster. Grid 384, 256 thr, 72 KB dynamic LDS (2 WGs/CU).

typedef unsigned short u16;
typedef __bf16 bf16x8 __attribute__((ext_vector_type(8)));
typedef float f32x4 __attribute__((ext_vector_type(4)));
typedef u16 u16x8 __attribute__((ext_vector_type(8)));

#define MFMA16(a,b,c) __builtin_amdgcn_mfma_f32_16x16x32_bf16((a),(b),(c),0,0,0)

__device__ __forceinline__ u16 f2bf(float f){
  unsigned u = __builtin_bit_cast(unsigned, f);
  u += 0x7fffu + ((u >> 16) & 1u);          // RN-even
  return (u16)(u >> 16);
}
__device__ __forceinline__ float bf2f(u16 s){
  unsigned u = ((unsigned)s) << 16;
  return __builtin_bit_cast(float, u);
}
__device__ __forceinline__ float sigm(float x){ return 1.f/(1.f+__expf(-x)); }
__device__ __forceinline__ float tanhfast(float x){ return 1.f - 2.f/(__expf(2.f*x)+1.f); }

__device__ __forceinline__ void ld_lds16(const u16* g, u16* l){
  __builtin_amdgcn_global_load_lds((const __attribute__((address_space(1))) void*)g,
                                   (__attribute__((address_space(3))) void*)l, 16, 0, 0);
}

// ---- f32 -> bf16 strided converter
__global__ void k_conv(const float* __restrict__ src, u16* __restrict__ dst,
                       long total, int srow, int sstride, int dstride, int doff){
  long i = ((long)blockIdx.x*blockDim.x + threadIdx.x)*8;
  if (i >= total) return;
  long r = i / srow;
  int  k = (int)(i - r*srow);
  const float* s = src + r*(long)sstride + k;
  u16x8 o;
  #pragma unroll
  for (int j=0;j<8;++j) o[j] = f2bf(s[j]);
  *(u16x8*)(dst + r*(long)dstride + doff + k) = o;
}

// ---- B-weight repack into stream blocks.
// dst granule p = (jt*nkt + kt)*512 + G, G = r*8 + s  (r=0..63 tile row, s=0..7)
// content: 8 bf16 from source row n = (r>>4)*1024 + jt*16 + (r&15)  (gate-ilv),
// cols kk..kk+7 with kk = kt*64 + ((s ^ (r&7))<<3)   (LDS swizzle baked in).
// kk < 1024 -> Wih, else Whh (kk-1024). For L0 pass nkt=16 (kk always < 1024).
__global__ void k_repackB(const float* __restrict__ Wih, const float* __restrict__ Whh,
                          u16* __restrict__ dst, int nkt){
  long p = (long)blockIdx.x*256 + threadIdx.x;
  int G = (int)(p & 511);
  long q = p >> 9;
  int kt = (int)(q % nkt);
  int jt = (int)(q / nkt);
  int r = G >> 3, s = G & 7;
  int kk = kt*64 + ((s ^ (r & 7)) << 3);
  int n = (r >> 4)*1024 + jt*16 + (r & 15);
  const float* src = (kk < 1024) ? Wih + (size_t)n*1024 + kk
                                 : Whh + (size_t)n*1024 + (kk - 1024);
  u16x8 o;
  #pragma unroll
  for (int j=0;j<8;++j) o[j] = f2bf(src[j]);
  *(u16x8*)(dst + p*8) = o;
}

// ---- misc prep: biases, pad-row zeroing, state init, gx_prop
__global__ void k_misc(const float* __restrict__ b_ih0, const float* __restrict__ b_hh0,
                       const float* __restrict__ b_ihr, const float* __restrict__ b_hhr,
                       const float* __restrict__ h0, const float* __restrict__ c0,
                       const float* __restrict__ props, const float* __restrict__ W_ih0,
                       u16* __restrict__ Ebf, u16* __restrict__ Wdec,
                       float* __restrict__ bias0, float* __restrict__ bcat,
                       u16* __restrict__ hbf0, float* __restrict__ cst, float* __restrict__ gxp){
  long i = (long)blockIdx.x*256 + threadIdx.x;
  if (i < 4096){ bias0[i] = b_ih0[i] + b_hh0[i]; return; }
  i -= 4096;
  if (i < 2*4096){ bcat[i] = b_ihr[i] + b_hhr[i]; return; }
  i -= 2*4096;
  if (i < 1024){ Ebf[47*1024 + i] = 0; Wdec[47*1024 + i] = 0; return; }
  i -= 1024;
  if (i < (long)3*256*1024){ hbf0[i] = f2bf(h0[i]); cst[i] = c0[i]; return; }
  i -= (long)3*256*1024;
  if (i < (long)256*4096){
    int b = (int)(i >> 12), n = (int)(i & 4095);
    const float* wr = W_ih0 + (long)n*1027 + 1024;
    gxp[i] = props[b*3+0]*wr[0] + props[b*3+1]*wr[1] + props[b*3+2]*wr[2];
  }
}

// ---- gx_emb[v][n] = sum_k E[v][k] * W_ih0[n][k]  (M=48 padded, N=4096, K=1024)
__global__ __launch_bounds__(64)
void k_gxemb(const u16* __restrict__ Ebf, const u16* __restrict__ Wih0b, float* __restrict__ gxe){
  const int lane = threadIdx.x;
  const int cl = lane & 15, ko = (lane >> 4)*8;
  const int m0 = blockIdx.x*16;
  const int n0 = blockIdx.y*16;
  f32x4 acc = {0.f,0.f,0.f,0.f};
  const u16* ap = Ebf   + (size_t)(m0+cl)*1024 + ko;
  const u16* bp = Wih0b + (size_t)(n0+cl)*1024 + ko;
  for (int k0=0; k0<1024; k0+=32){
    bf16x8 a = *(const bf16x8*)(ap + k0);
    bf16x8 b = *(const bf16x8*)(bp + k0);
    acc = MFMA16(a, b, acc);
  }
  const int rbase = (lane >> 4)*4;
  #pragma unroll
  for (int q=0;q<4;++q){
    int v = m0 + rbase + q;
    if (v < 47) gxe[(size_t)v*4096 + n0 + cl] = acc[q];
  }
}

// ---- one tile of one (layer, t): TM=128 x TN=64, BK=64, 3 LDS slots,
// 2-deep prefetch, one barrier per chunk. 4 waves, wave = 32m x 64n.
template<int LAYER>
__device__ __forceinline__ void diag_tile(int mt, int jt, int t,
    const int* __restrict__ x, u16* __restrict__ hbf, u16* __restrict__ outsb,
    float* __restrict__ cst, const u16* __restrict__ Wpk,
    const float* __restrict__ bias0, const float* __restrict__ bcat,
    const float* __restrict__ gxe, const float* __restrict__ gxp, u16* lds)
{
  constexpr int NT = (LAYER==0) ? 16 : 32;
  const int tid = threadIdx.x;
  const int lane = tid & 63, w = tid >> 6;
  const int cl = lane & 15, hi = lane >> 4;
  const size_t BH = (size_t)256*1024;
  const int p = t & 1;

  const u16* hp = hbf + ((size_t)p*3 + LAYER)*BH;       // own h @ t-1
  u16*       hn = hbf + ((size_t)(p^1)*3 + LAYER)*BH;   // own h @ t
  float*     cc = cst + (size_t)LAYER*BH;
  const u16* xb = (LAYER>0) ? hbf + ((size_t)(p^1)*3 + (LAYER-1))*BH : (const u16*)0;
  // contiguous per-(layer,jt) weight stream block
  const u16* Bblk = (LAYER==0) ? Wpk + (size_t)jt*65536
                  : Wpk + (size_t)4194304 + (size_t)(LAYER-1)*8388608 + (size_t)jt*131072;
  const int m_base = mt*128;
  const int m0w = w*32;

  // 3 slots x 24 KB: A (8192 u16) + B (4096 u16)
  u16* slot0 = lds;
  u16* slot1 = lds + 12288;
  u16* slot2 = lds + 24576;
  u16* const slots[3] = { slot0, slot1, slot2 };

  auto stage = [&](int s, int kt){
    const int kbase = kt*64;
    u16* sA = slots[s];
    u16* sB = slots[s] + 8192;
    #pragma unroll
    for (int j=0; j<4; ++j){                   // A: 1024 granules / 256 thr
      int G = j*256 + tid;
      int r = G >> 3;
      int kk = kbase + (((G & 7) ^ (r & 7)) << 3);   // src pre-swizzle
      const u16* src;
      if (LAYER > 0)
        src = (kk < 1024) ? xb + (size_t)(m_base+r)*1024 + kk
                          : hp + (size_t)(m_base+r)*1024 + (kk - 1024);
      else
        src = hp + (size_t)(m_base+r)*1024 + kk;
      ld_lds16(src, sA + (size_t)G*8);
    }
    #pragma unroll
    for (int j=0; j<2; ++j){                   // B: contiguous stream, 512 granules
      int G = j*256 + tid;
      ld_lds16(Bblk + (size_t)kt*4096 + (size_t)G*8, sB + (size_t)G*8);
    }
  };

  f32x4 acc[2][4];
  #pragma unroll
  for (int mf=0; mf<2; ++mf)
    #pragma unroll
    for (int g=0; g<4; ++g)
      acc[mf][g] = (f32x4){0.f,0.f,0.f,0.f};

  stage(0, 0);
  stage(1, 1);
  for (int kt=0; kt<NT; ++kt){
    if (kt == NT-1) asm volatile("s_waitcnt vmcnt(0)" ::: "memory");
    else            asm volatile("s_waitcnt vmcnt(6)" ::: "memory");
    __builtin_amdgcn_s_barrier();
    asm volatile("" ::: "memory");
    if (kt+2 < NT) stage((kt+2)%3, kt+2);      // overwrites slot of chunk kt-1 (safe)
    const u16* A = slots[kt%3];
    const u16* B = slots[kt%3] + 8192;
    __builtin_amdgcn_s_setprio(1);
    #pragma unroll
    for (int half=0; half<2; ++half){
      const int kg = half*4 + hi;              // granule index (swizzled read)
      bf16x8 a0, a1, b[4];
      { int r = m0w + cl;      a0 = *(const bf16x8*)(A + r*64 + ((kg ^ (r&7))<<3)); }
      { int r = m0w + 16 + cl; a1 = *(const bf16x8*)(A + r*64 + ((kg ^ (r&7))<<3)); }
      #pragma unroll
      for (int g=0; g<4; ++g){
        int r = g*16 + cl;
        b[g] = *(const bf16x8*)(B + r*64 + ((kg ^ (r&7))<<3));
      }
      #pragma unroll
      for (int g=0; g<4; ++g){
        acc[0][g] = MFMA16(a0, b[g], acc[0][g]);
        acc[1][g] = MFMA16(a1, b[g], acc[1][g]);
      }
    }
    __builtin_amdgcn_s_setprio(0);
    asm volatile("" ::: "memory");
  }

  // fused LSTM cell. C/D: col = cl (-> hcol within tile), row = hi*4+q (-> batch)
  const int hcol = jt*16 + cl;
  const float* bias = (LAYER==0) ? bias0 : bcat + (size_t)(LAYER-1)*4096;
  const float bi_ = bias[hcol], bf_ = bias[1024+hcol],
              bg_ = bias[2048+hcol], bo_ = bias[3072+hcol];
  #pragma unroll
  for (int mf=0; mf<2; ++mf){
    #pragma unroll
    for (int q=0; q<4; ++q){
      const int row = m_base + m0w + mf*16 + hi*4 + q;
      float gi = acc[mf][0][q] + bi_;
      float gf = acc[mf][1][q] + bf_;
      float gg = acc[mf][2][q] + bg_;
      float go = acc[mf][3][q] + bo_;
      if (LAYER == 0){
        const int tok = (t==0) ? 1 : x[row*100 + t];
        const float* ge = gxe + (size_t)tok*4096;
        const float* gp = gxp + (size_t)row*4096;
        gi += ge[hcol]        + gp[hcol];
        gf += ge[1024 + hcol] + gp[1024 + hcol];
        gg += ge[2048 + hcol] + gp[2048 + hcol];
        go += ge[3072 + hcol] + gp[3072 + hcol];
      }
      const float i_ = sigm(gi), f_ = sigm(gf), o_ = sigm(go), g_ = tanhfast(gg);
      const size_t off = (size_t)row*1024 + hcol;
      const float cn = f_*cc[off] + i_*g_;
      cc[off] = cn;
      const u16 hb = f2bf(o_*tanhfast(cn));
      hn[off] = hb;
      if (LAYER == 2) outsb[(size_t)t*BH + off] = hb;
    }
  }
}

// grid = 384: id = slot + 192*mt; slot = layer*64 + jt  (xcd = id%8 stable
// across dispatches; both mt copies of a jt share an XCD)
__global__ __launch_bounds__(256)
void k_diag(int d, const int* __restrict__ x, u16* __restrict__ hbf,
            u16* __restrict__ outsb, float* __restrict__ cst,
            const u16* __restrict__ Wpk,
            const float* __restrict__ bias0, const float* __restrict__ bcat,
            const float* __restrict__ gxe, const float* __restrict__ gxp)
{
  extern __shared__ u16 lds[];
  const int id = blockIdx.x;
  const int mt = id / 192;
  const int slot = id - mt*192;
  const int layer = slot >> 6;
  const int jt = slot & 63;
  const int t = d - layer;
  if (t < 0 || t >= 99) return;
  if (layer == 0)
    diag_tile<0>(mt, jt, t, x, hbf, outsb, cst, Wpk, bias0, bcat, gxe, gxp, lds);
  else if (layer == 1)
    diag_tile<1>(mt, jt, t, x, hbf, outsb, cst, Wpk, bias0, bcat, gxe, gxp, lds);
  else
    diag_tile<2>(mt, jt, t, x, hbf, outsb, cst, Wpk, bias0, bcat, gxe, gxp, lds);
}

// ---- decoder: logits[b,t,v] = outs[t,b,:] . Wdec[v,:] + b_dec[v]
__global__ __launch_bounds__(256)
void k_decode(const u16* __restrict__ outs, const u16* __restrict__ Wdec,
              const float* __restrict__ bdec, float* __restrict__ logits){
  const int lane = threadIdx.x & 63, w = threadIdx.x >> 6;
  const int cl = lane & 15, ko = (lane >> 4)*8;
  const size_t m0 = ((size_t)blockIdx.x*4 + w)*16;
  const u16* ap = outs + (m0+cl)*1024 + ko;
  f32x4 acc[3];
  #pragma unroll
  for (int nt=0; nt<3; ++nt) acc[nt] = (f32x4){0.f,0.f,0.f,0.f};
  const u16* bp = Wdec + (size_t)cl*1024 + ko;
  for (int k0=0; k0<1024; k0+=32){
    bf16x8 a = *(const bf16x8*)(ap + k0);
    #pragma unroll
    for (int nt=0; nt<3; ++nt){
      bf16x8 b = *(const bf16x8*)(bp + (size_t)nt*16*1024 + k0);
      acc[nt] = MFMA16(a, b, acc[nt]);
    }
  }
  const int rbase = (lane >> 4)*4;
  #pragma unroll
  for (int nt=0; nt<3; ++nt){
    #pragma unroll
    for (int q=0; q<4; ++q){
      int v = nt*16 + cl;
      if (v < 47){
        size_t row = m0 + rbase + q;   // row = t*256 + b
        int tt = (int)(row >> 8);
        int b  = (int)(row & 255);
        logits[((size_t)b*99 + tt)*47 + v] = acc[nt][q] + bdec[v];
      }
    }
  }
}

// ---- final hT / cT copy-out
__global__ void k_final(const u16* __restrict__ hb, const float* __restrict__ cst, float* __restrict__ out){
  int i = blockIdx.x*256 + threadIdx.x;
  if (i < 3*256*1024){
    out[1191168 + i]          = bf2f(hb[i]);
    out[1191168 + 786432 + i] = cst[i];
  }
}

extern "C" void kernel_launch(void* const* d_in, const int* in_sizes, int n_in,
                              void* d_out, int out_size, void* d_ws, size_t ws_size,
                              hipStream_t stream) {
  (void)in_sizes; (void)n_in; (void)out_size; (void)ws_size;
  const int*   x      = (const int*)  d_in[0];
  const float* props  = (const float*)d_in[1];
  const float* h0     = (const float*)d_in[2];
  const float* c0     = (const float*)d_in[3];
  const float* E      = (const float*)d_in[4];
  const float* W_ih0  = (const float*)d_in[5];
  const float* W_hh0  = (const float*)d_in[6];
  const float* b_ih0  = (const float*)d_in[7];
  const float* b_hh0  = (const float*)d_in[8];
  const float* W_ih_r = (const float*)d_in[9];
  const float* W_hh_r = (const float*)d_in[10];
  const float* b_ih_r = (const float*)d_in[11];
  const float* b_hh_r = (const float*)d_in[12];
  const float* W_dec  = (const float*)d_in[13];
  const float* b_dec  = (const float*)d_in[14];
  float* out = (float*)d_out;

  // workspace layout (~114 MB)
  u16* Wpk   = (u16*)d_ws;                          // 20,971,520 u16: L0 4M | L1 8M | L2 8M
  u16* Wdec  = Wpk   + (size_t)20971520;            // 48*1024 (row 47 = 0)
  u16* Wih0b = Wdec  + (size_t)49152;               // 4096*1024 (first 1024 cols of W_ih0)
  u16* Ebf   = Wih0b + (size_t)4194304;             // 48*1024 (row 47 = 0)
  u16* hbf   = Ebf   + (size_t)49152;               // 2 * 3*256*1024 (dbuf h, bf16)
  u16* outsb = hbf   + (size_t)1572864;             // 99*256*1024
  float* gxe   = (float*)(outsb + (size_t)25952256);// 48*4096
  float* gxp   = gxe   + (size_t)196608;            // 256*4096
  float* bias0 = gxp   + (size_t)1048576;           // 4096
  float* bcat  = bias0 + 4096;                      // 2*4096
  float* cst   = bcat  + 8192;                      // 3*256*1024 f32

  // ---- prep
  k_repackB<<<2048, 256, 0, stream>>>(W_hh0, W_hh0, Wpk, 16);
  k_repackB<<<4096, 256, 0, stream>>>(W_ih_r, W_hh_r, Wpk + (size_t)4194304, 32);
  k_repackB<<<4096, 256, 0, stream>>>(W_ih_r + (size_t)4096*1024,
                                      W_hh_r + (size_t)4096*1024,
                                      Wpk + (size_t)12582912, 32);
  k_conv<<<2048, 256, 0, stream>>>(W_ih0, Wih0b, (long)4096*1024, 1024, 1027, 1024, 0);
  k_conv<<<24,   256, 0, stream>>>(E,     Ebf,   (long)47*1024,   1024, 1024, 1024, 0);
  k_conv<<<24,   256, 0, stream>>>(W_dec, Wdec,  (long)47*1024,   1024, 1024, 1024, 0);
  k_misc<<<7221, 256, 0, stream>>>(b_ih0, b_hh0, b_ih_r, b_hh_r, h0, c0, props, W_ih0,
                                   Ebf, Wdec, bias0, bcat, hbf, cst, gxp);
  k_gxemb<<<dim3(3,256), 64, 0, stream>>>(Ebf, Wih0b, gxe);

  // ---- diagonal recurrence: dispatch d runs (L0@d, L1@d-1, L2@d-2)
  hipFuncSetAttribute(reinterpret_cast<const void*>(k_diag),
                      hipFuncAttributeMaxDynamicSharedMemorySize, 73728);
  for (int d = 0; d < 101; ++d){
    k_diag<<<384, 256, 73728, stream>>>(d, x, hbf, outsb, cst, Wpk,
                                        bias0, bcat, gxe, gxp);
  }

  // ---- decode + final states (last write at t=98 -> state buffer 1)
  k_decode<<<396, 256, 0, stream>>>(outsb, Wdec, b_dec, out);
  k_final<<<3072, 256, 0, stream>>>(hbf + (size_t)1572864/2*0 + (size_t)3*256*1024, cst, out);
}

// Round 8
// 2758.305 us; speedup vs baseline: 9.7768x; 1.4027x over previous
//
#include <hip/hip_runtime.h>

// ConditionalSmilesRnn: 3-layer LSTM, B=256, H=1024, steps=99, V=47, P=3.
// R8 (= R7 + compile fix): split recurrence. Diagonal dispatches (skew 4/layer)
// run ONLY the W_hh h-GEMMs (24 MB total, 3 MB/XCD -> L2-resident) + fused
// cells. The W_ih x-GEMMs are batched: every 4 steps, k_xp computes a
// 1024x4096x1024 GEMM (xpart, bf16) consumed by the cell epilogue like a bias.
// h kept in 8-slot history rings (also the xpart inputs). Uniform NT=16 tiles.

typedef unsigned short u16;
typedef __bf16 bf16x8 __attribute__((ext_vector_type(8)));
typedef float f32x4 __attribute__((ext_vector_type(4)));
typedef u16 u16x8 __attribute__((ext_vector_type(8)));

#define MFMA16(a,b,c) __builtin_amdgcn_mfma_f32_16x16x32_bf16((a),(b),(c),0,0,0)
#define BH 262144

__device__ __forceinline__ u16 f2bf(float f){
  unsigned u = __builtin_bit_cast(unsigned, f);
  u += 0x7fffu + ((u >> 16) & 1u);          // RN-even
  return (u16)(u >> 16);
}
__device__ __forceinline__ float bf2f(u16 s){
  unsigned u = ((unsigned)s) << 16;
  return __builtin_bit_cast(float, u);
}
__device__ __forceinline__ float sigm(float x){ return 1.f/(1.f+__expf(-x)); }
__device__ __forceinline__ float tanhfast(float x){ return 1.f - 2.f/(__expf(2.f*x)+1.f); }

__device__ __forceinline__ void ld_lds16(const u16* g, u16* l){
  __builtin_amdgcn_global_load_lds((const __attribute__((address_space(1))) void*)g,
                                   (__attribute__((address_space(3))) void*)l, 16, 0, 0);
}

// ---- f32 -> bf16 strided converter
__global__ void k_conv(const float* __restrict__ src, u16* __restrict__ dst,
                       long total, int srow, int sstride, int dstride, int doff){
  long i = ((long)blockIdx.x*blockDim.x + threadIdx.x)*8;
  if (i >= total) return;
  long r = i / srow;
  int  k = (int)(i - r*srow);
  const float* s = src + r*(long)sstride + k;
  u16x8 o;
  #pragma unroll
  for (int j=0;j<8;++j) o[j] = f2bf(s[j]);
  *(u16x8*)(dst + r*(long)dstride + doff + k) = o;
}

// ---- weight repack into per-(jt) contiguous stream blocks (K=1024, nkt=16).
// granule p = (jt*16 + kt)*512 + r*8 + s; src row n = (r>>4)*1024 + jt*16 + (r&15);
// cols kk = kt*64 + ((s ^ (r&7))<<3)  (LDS swizzle baked in).
__global__ void k_repackB(const float* __restrict__ Wih, const float* __restrict__ Whh,
                          u16* __restrict__ dst, int nkt){
  long p = (long)blockIdx.x*256 + threadIdx.x;
  int G = (int)(p & 511);
  long q = p >> 9;
  int kt = (int)(q % nkt);
  int jt = (int)(q / nkt);
  int r = G >> 3, s = G & 7;
  int kk = kt*64 + ((s ^ (r & 7)) << 3);
  int n = (r >> 4)*1024 + jt*16 + (r & 15);
  const float* src = (kk < 1024) ? Wih + (size_t)n*1024 + kk
                                 : Whh + (size_t)n*1024 + (kk - 1024);
  u16x8 o;
  #pragma unroll
  for (int j=0;j<8;++j) o[j] = f2bf(src[j]);
  *(u16x8*)(dst + p*8) = o;
}

// ---- misc prep: biases, pad-row zeroing, state init (hist rings), gx_prop
__global__ void k_misc(const float* __restrict__ b_ih0, const float* __restrict__ b_hh0,
                       const float* __restrict__ b_ihr, const float* __restrict__ b_hhr,
                       const float* __restrict__ h0, const float* __restrict__ c0,
                       const float* __restrict__ props, const float* __restrict__ W_ih0,
                       u16* __restrict__ Ebf, u16* __restrict__ Wdec,
                       float* __restrict__ bias0, float* __restrict__ bcat,
                       u16* __restrict__ hist0, u16* __restrict__ hist1,
                       u16* __restrict__ outsbF,
                       float* __restrict__ cst, float* __restrict__ gxp){
  long i = (long)blockIdx.x*256 + threadIdx.x;
  if (i < 4096){ bias0[i] = b_ih0[i] + b_hh0[i]; return; }
  i -= 4096;
  if (i < 2*4096){ bcat[i] = b_ihr[i] + b_hhr[i]; return; }
  i -= 2*4096;
  if (i < 1024){ Ebf[47*1024 + i] = 0; Wdec[47*1024 + i] = 0; return; }
  i -= 1024;
  if (i < (long)3*BH){
    int l = (int)(i >> 18); long r = i & (BH-1);
    u16 v = f2bf(h0[i]);
    if (l==0)      hist0[(size_t)7*BH + r] = v;
    else if (l==1) hist1[(size_t)7*BH + r] = v;
    else           outsbF[r] = v;
    cst[i] = c0[i];
    return;
  }
  i -= (long)3*BH;
  if (i < (long)256*4096){
    int b = (int)(i >> 12), n = (int)(i & 4095);
    const float* wr = W_ih0 + (long)n*1027 + 1024;
    gxp[i] = props[b*3+0]*wr[0] + props[b*3+1]*wr[1] + props[b*3+2]*wr[2];
  }
}

// ---- gx_emb[v][n] = sum_k E[v][k] * W_ih0[n][k]  (M=48 padded, N=4096, K=1024)
__global__ __launch_bounds__(64)
void k_gxemb(const u16* __restrict__ Ebf, const u16* __restrict__ Wih0b, float* __restrict__ gxe){
  const int lane = threadIdx.x;
  const int cl = lane & 15, ko = (lane >> 4)*8;
  const int m0 = blockIdx.x*16;
  const int n0 = blockIdx.y*16;
  f32x4 acc = {0.f,0.f,0.f,0.f};
  const u16* ap = Ebf   + (size_t)(m0+cl)*1024 + ko;
  const u16* bp = Wih0b + (size_t)(n0+cl)*1024 + ko;
  for (int k0=0; k0<1024; k0+=32){
    bf16x8 a = *(const bf16x8*)(ap + k0);
    bf16x8 b = *(const bf16x8*)(bp + k0);
    acc = MFMA16(a, b, acc);
  }
  const int rbase = (lane >> 4)*4;
  #pragma unroll
  for (int q=0;q<4;++q){
    int v = m0 + rbase + q;
    if (v < 47) gxe[(size_t)v*4096 + n0 + cl] = acc[q];
  }
}

// ================= shared K-loop (TM=128 x TN=64, K=1024, NT=16) =================
// 3 LDS slots x 24KB (pointer arithmetic only -- no pointer arrays: LDS
// addrspacecast in a static initializer doesn't compile), 2-deep prefetch,
// one barrier per chunk, counted vmcnt.
#define KLOOP_BODY(APTR_EXPR)                                                   \
  auto stage = [&](int s, int kt){                                              \
    const int kbase = kt*64;                                                    \
    u16* sA = lds + (size_t)s*12288;                                            \
    u16* sB = sA + 8192;                                                        \
    _Pragma("unroll")                                                           \
    for (int j=0;j<4;++j){                                                      \
      int G = j*256 + tid; int r = G >> 3;                                      \
      int kk = kbase + (((G & 7) ^ (r & 7)) << 3);                              \
      ld_lds16(APTR_EXPR, sA + (size_t)G*8);                                    \
    }                                                                           \
    _Pragma("unroll")                                                           \
    for (int j=0;j<2;++j){                                                      \
      int G = j*256 + tid;                                                      \
      ld_lds16(Bblk + (size_t)kt*4096 + (size_t)G*8, sB + (size_t)G*8);         \
    }                                                                           \
  };                                                                            \
  f32x4 acc[2][4];                                                              \
  _Pragma("unroll")                                                             \
  for (int mf=0; mf<2; ++mf)                                                    \
    _Pragma("unroll")                                                           \
    for (int g=0; g<4; ++g) acc[mf][g] = (f32x4){0.f,0.f,0.f,0.f};              \
  stage(0,0); stage(1,1);                                                       \
  for (int kt=0; kt<16; ++kt){                                                  \
    if (kt == 15) asm volatile("s_waitcnt vmcnt(0)" ::: "memory");              \
    else          asm volatile("s_waitcnt vmcnt(6)" ::: "memory");              \
    __builtin_amdgcn_s_barrier();                                               \
    asm volatile("" ::: "memory");                                              \
    if (kt+2 < 16) stage((kt+2)%3, kt+2);                                       \
    const u16* A = lds + (size_t)(kt%3)*12288;                                  \
    const u16* B = A + 8192;                                                    \
    __builtin_amdgcn_s_setprio(1);                                              \
    _Pragma("unroll")                                                           \
    for (int half=0; half<2; ++half){                                           \
      const int kg = half*4 + hi;                                               \
      bf16x8 a0, a1, b[4];                                                      \
      { int r = m0w + cl;      a0 = *(const bf16x8*)(A + r*64 + ((kg ^ (r&7))<<3)); } \
      { int r = m0w + 16 + cl; a1 = *(const bf16x8*)(A + r*64 + ((kg ^ (r&7))<<3)); } \
      _Pragma("unroll")                                                         \
      for (int g=0; g<4; ++g){                                                  \
        int r = g*16 + cl;                                                      \
        b[g] = *(const bf16x8*)(B + r*64 + ((kg ^ (r&7))<<3));                  \
      }                                                                         \
      _Pragma("unroll")                                                         \
      for (int g=0; g<4; ++g){                                                  \
        acc[0][g] = MFMA16(a0, b[g], acc[0][g]);                                \
        acc[1][g] = MFMA16(a1, b[g], acc[1][g]);                                \
      }                                                                         \
    }                                                                           \
    __builtin_amdgcn_s_setprio(0);                                              \
    asm volatile("" ::: "memory");                                              \
  }

// ---- diag tile: gates = W_hh . h_prev (+ gxe/gxp or xpart) + bias; fused cell.
template<int LAYER>
__device__ __forceinline__ void diagh_tile(int mt, int jt, int t,
    const int* __restrict__ x, const u16* hp, u16* aux, float* cc,
    const u16* __restrict__ Bblk, const float* __restrict__ bias,
    const float* __restrict__ gxe, const float* __restrict__ gxp,
    const u16* xpt, u16* lds)
{
  const int tid = threadIdx.x;
  const int lane = tid & 63, w = tid >> 6;
  const int cl = lane & 15, hi = lane >> 4;
  const int m_base = mt*128, m0w = w*32;

  KLOOP_BODY(hp + (size_t)(m_base + r)*1024 + kk)

  // fused LSTM cell. C/D: col = cl (-> hcol), row = hi*4+q (-> batch)
  const int hcol = jt*16 + cl;
  const float bi_ = bias[hcol], bf_ = bias[1024+hcol],
              bg_ = bias[2048+hcol], bo_ = bias[3072+hcol];
  #pragma unroll
  for (int mf=0; mf<2; ++mf){
    #pragma unroll
    for (int q=0; q<4; ++q){
      const int row = m_base + m0w + mf*16 + hi*4 + q;
      float gi = acc[mf][0][q] + bi_;
      float gf = acc[mf][1][q] + bf_;
      float gg = acc[mf][2][q] + bg_;
      float go = acc[mf][3][q] + bo_;
      if (LAYER == 0){
        const int tok = (t==0) ? 1 : x[row*100 + t];
        const float* ge = gxe + (size_t)tok*4096;
        const float* gp = gxp + (size_t)row*4096;
        gi += ge[hcol]        + gp[hcol];
        gf += ge[1024 + hcol] + gp[1024 + hcol];
        gg += ge[2048 + hcol] + gp[2048 + hcol];
        go += ge[3072 + hcol] + gp[3072 + hcol];
      } else {
        const u16* xr = xpt + (size_t)row*4096;
        gi += bf2f(xr[hcol]);
        gf += bf2f(xr[1024 + hcol]);
        gg += bf2f(xr[2048 + hcol]);
        go += bf2f(xr[3072 + hcol]);
      }
      const float i_ = sigm(gi), f_ = sigm(gf), o_ = sigm(go), g_ = tanhfast(gg);
      const size_t off = (size_t)row*1024 + hcol;
      const float cn = f_*cc[off] + i_*g_;
      cc[off] = cn;
      aux[off] = f2bf(o_*tanhfast(cn));
    }
  }
}

// grid 384: id = slot + 192*mt, slot = layer*64 + jt  (xcd = slot%8, stable)
__global__ __launch_bounds__(256)
void k_diag(int d, const int* __restrict__ x, u16* hist0, u16* hist1, u16* outsbF,
            float* __restrict__ cst, const u16* __restrict__ WpkH,
            const float* __restrict__ bias0, const float* __restrict__ bcat,
            const float* __restrict__ gxe, const float* __restrict__ gxp,
            const u16* __restrict__ xp1, const u16* __restrict__ xp2)
{
  extern __shared__ u16 lds[];
  const int id = blockIdx.x;
  const int mt = id / 192;
  const int slot = id - mt*192;
  const int layer = slot >> 6;
  const int jt = slot & 63;
  const int t = d - 4*layer;
  if (t < 0 || t > 98) return;
  if (layer == 0){
    diagh_tile<0>(mt, jt, t, x, hist0 + (size_t)((t+7)&7)*BH, hist0 + (size_t)(t&7)*BH,
                  cst, WpkH + (size_t)jt*65536, bias0, gxe, gxp, nullptr, lds);
  } else if (layer == 1){
    const u16* xpt = xp1 + (size_t)((((t>>2)&1)<<2) + (t&3))*1048576;
    diagh_tile<1>(mt, jt, t, x, hist1 + (size_t)((t+7)&7)*BH, hist1 + (size_t)(t&7)*BH,
                  cst + BH, WpkH + (size_t)4194304 + (size_t)jt*65536, bcat,
                  nullptr, nullptr, xpt, lds);
  } else {
    const u16* xpt = xp2 + (size_t)((((t>>2)&1)<<2) + (t&3))*1048576;
    diagh_tile<2>(mt, jt, t, x, outsbF + (size_t)t*BH, outsbF + (size_t)(t+1)*BH,
                  cst + 2*BH, WpkH + (size_t)8388608 + (size_t)jt*65536, bcat + 4096,
                  nullptr, nullptr, xpt, lds);
  }
}

// ---- batched xpart GEMM: window w (4 steps), M=1024, N=4096, K=1024 -> bf16
// grid 512: id = mt*64 + jt (xcd = jt%8); mt: t' = mt>>1, m-half = mt&1.
__global__ __launch_bounds__(256)
void k_xp(int w, const u16* __restrict__ hist, const u16* __restrict__ Wblk,
          u16* __restrict__ xpout)
{
  extern __shared__ u16 lds[];
  const int id = blockIdx.x;
  const int mt = id >> 6, jt = id & 63;
  const int tid = threadIdx.x;
  const int lane = tid & 63, wv = tid >> 6;
  const int cl = lane & 15, hi = lane >> 4;
  const int tprime = mt >> 1;
  const int m_base = (mt & 1)*128, m0w = wv*32;
  const u16* hp = hist + (size_t)((4*w + tprime) & 7)*BH;
  const u16* Bblk = Wblk + (size_t)jt*65536;

  KLOOP_BODY(hp + (size_t)(m_base + r)*1024 + kk)

  const int hcol = jt*16 + cl;
  u16* xpo = xpout + (size_t)(((w&1)<<2) + tprime)*1048576;
  #pragma unroll
  for (int mf=0; mf<2; ++mf){
    #pragma unroll
    for (int q=0; q<4; ++q){
      const int m = m_base + m0w + mf*16 + hi*4 + q;
      u16* xr = xpo + (size_t)m*4096 + hcol;
      xr[0]    = f2bf(acc[mf][0][q]);
      xr[1024] = f2bf(acc[mf][1][q]);
      xr[2048] = f2bf(acc[mf][2][q]);
      xr[3072] = f2bf(acc[mf][3][q]);
    }
  }
}

// ---- decoder: logits[b,t,v] = outs[t,b,:] . Wdec[v,:] + b_dec[v]
__global__ __launch_bounds__(256)
void k_decode(const u16* __restrict__ outs, const u16* __restrict__ Wdec,
              const float* __restrict__ bdec, float* __restrict__ logits){
  const int lane = threadIdx.x & 63, w = threadIdx.x >> 6;
  const int cl = lane & 15, ko = (lane >> 4)*8;
  const size_t m0 = ((size_t)blockIdx.x*4 + w)*16;
  const u16* ap = outs + (m0+cl)*1024 + ko;
  f32x4 acc[3];
  #pragma unroll
  for (int nt=0; nt<3; ++nt) acc[nt] = (f32x4){0.f,0.f,0.f,0.f};
  const u16* bp = Wdec + (size_t)cl*1024 + ko;
  for (int k0=0; k0<1024; k0+=32){
    bf16x8 a = *(const bf16x8*)(ap + k0);
    #pragma unroll
    for (int nt=0; nt<3; ++nt){
      bf16x8 b = *(const bf16x8*)(bp + (size_t)nt*16*1024 + k0);
      acc[nt] = MFMA16(a, b, acc[nt]);
    }
  }
  const int rbase = (lane >> 4)*4;
  #pragma unroll
  for (int nt=0; nt<3; ++nt){
    #pragma unroll
    for (int q=0; q<4; ++q){
      int v = nt*16 + cl;
      if (v < 47){
        size_t row = m0 + rbase + q;   // row = t*256 + b
        int tt = (int)(row >> 8);
        int b  = (int)(row & 255);
        logits[((size_t)b*99 + tt)*47 + v] = acc[nt][q] + bdec[v];
      }
    }
  }
}

// ---- final hT / cT copy-out (t=98: hist slot 2, outsbF slot 99)
__global__ void k_final(const u16* __restrict__ h0s, const u16* __restrict__ h1s,
                        const u16* __restrict__ h2s, const float* __restrict__ cst,
                        float* __restrict__ out){
  long i = (long)blockIdx.x*256 + threadIdx.x;
  if (i < (long)3*BH){
    int l = (int)(i >> 18); long r = i & (BH-1);
    const u16* src = (l==0) ? h0s : (l==1) ? h1s : h2s;
    out[1191168 + i] = bf2f(src[r]);
    out[1191168 + 786432 + i] = cst[i];
  }
}

extern "C" void kernel_launch(void* const* d_in, const int* in_sizes, int n_in,
                              void* d_out, int out_size, void* d_ws, size_t ws_size,
                              hipStream_t stream) {
  (void)in_sizes; (void)n_in; (void)out_size; (void)ws_size;
  const int*   x      = (const int*)  d_in[0];
  const float* props  = (const float*)d_in[1];
  const float* h0     = (const float*)d_in[2];
  const float* c0     = (const float*)d_in[3];
  const float* E      = (const float*)d_in[4];
  const float* W_ih0  = (const float*)d_in[5];
  const float* W_hh0  = (const float*)d_in[6];
  const float* b_ih0  = (const float*)d_in[7];
  const float* b_hh0  = (const float*)d_in[8];
  const float* W_ih_r = (const float*)d_in[9];
  const float* W_hh_r = (const float*)d_in[10];
  const float* b_ih_r = (const float*)d_in[11];
  const float* b_hh_r = (const float*)d_in[12];
  const float* W_dec  = (const float*)d_in[13];
  const float* b_dec  = (const float*)d_in[14];
  float* out = (float*)d_out;

  // workspace layout (~145 MB)
  u16* WpkH   = (u16*)d_ws;                 // 3 x 4,194,304 (W_hh stream blocks)
  u16* WpkI   = WpkH  + (size_t)12582912;   // 2 x 4,194,304 (W_ih_r stream blocks)
  u16* Wdec   = WpkI  + (size_t)8388608;    // 48*1024 (row 47 = 0)
  u16* Ebf    = Wdec  + (size_t)49152;      // 48*1024 (row 47 = 0)
  u16* hist0  = Ebf   + (size_t)49152;      // 8 x BH  (h0 ring; slot 7 = init)
  u16* hist1  = hist0 + (size_t)8*BH;       // 8 x BH
  u16* outsbF = hist1 + (size_t)8*BH;       // 100 x BH (slot 0 = h2 init; t -> t+1)
  u16* xp1    = outsbF + (size_t)100*BH;    // 2 win x 4 steps x 256 x 4096
  u16* xp2    = xp1   + (size_t)8388608;    // same
  u16* Wih0b  = xp1;                        // ALIAS: prep-only, dead before xp writes
  float* gxe   = (float*)(xp2 + (size_t)8388608); // 48*4096
  float* gxp   = gxe   + (size_t)196608;          // 256*4096
  float* bias0 = gxp   + (size_t)1048576;         // 4096
  float* bcat  = bias0 + 4096;                    // 2*4096
  float* cst   = bcat  + 8192;                    // 3 x BH f32

  // ---- prep
  k_repackB<<<2048, 256, 0, stream>>>(W_hh0, W_hh0, WpkH, 16);
  k_repackB<<<2048, 256, 0, stream>>>(W_hh_r, W_hh_r, WpkH + (size_t)4194304, 16);
  k_repackB<<<2048, 256, 0, stream>>>(W_hh_r + (size_t)4194304, W_hh_r + (size_t)4194304,
                                      WpkH + (size_t)8388608, 16);
  k_repackB<<<2048, 256, 0, stream>>>(W_ih_r, W_ih_r, WpkI, 16);
  k_repackB<<<2048, 256, 0, stream>>>(W_ih_r + (size_t)4194304, W_ih_r + (size_t)4194304,
                                      WpkI + (size_t)4194304, 16);
  k_conv<<<2048, 256, 0, stream>>>(W_ih0, Wih0b, (long)4096*1024, 1024, 1027, 1024, 0);
  k_conv<<<24,   256, 0, stream>>>(E,     Ebf,   (long)47*1024,   1024, 1024, 1024, 0);
  k_conv<<<24,   256, 0, stream>>>(W_dec, Wdec,  (long)47*1024,   1024, 1024, 1024, 0);
  k_misc<<<7221, 256, 0, stream>>>(b_ih0, b_hh0, b_ih_r, b_hh_r, h0, c0, props, W_ih0,
                                   Ebf, Wdec, bias0, bcat, hist0, hist1, outsbF, cst, gxp);
  k_gxemb<<<dim3(3,256), 64, 0, stream>>>(Ebf, Wih0b, gxe);

  // ---- recurrence: diag d runs (L0@d, L1@d-4, L2@d-8); xpart GEMMs every 4 d
  (void)hipFuncSetAttribute(reinterpret_cast<const void*>(k_diag),
                            hipFuncAttributeMaxDynamicSharedMemorySize, 73728);
  (void)hipFuncSetAttribute(reinterpret_cast<const void*>(k_xp),
                            hipFuncAttributeMaxDynamicSharedMemorySize, 73728);
  for (int d = 0; d < 107; ++d){
    k_diag<<<384, 256, 73728, stream>>>(d, x, hist0, hist1, outsbF, cst,
                                        WpkH, bias0, bcat, gxe, gxp, xp1, xp2);
    if (d >= 3 && ((d-3) & 3) == 0){
      int w = (d-3) >> 2;
      if (w < 25) k_xp<<<512, 256, 73728, stream>>>(w, hist0, WpkI, xp1);
    }
    if (d >= 7 && ((d-7) & 3) == 0){
      int w = (d-7) >> 2;
      if (w < 25) k_xp<<<512, 256, 73728, stream>>>(w, hist1, WpkI + (size_t)4194304, xp2);
    }
  }

  // ---- decode + final states
  k_decode<<<396, 256, 0, stream>>>(outsbF + (size_t)BH, Wdec, b_dec, out);
  k_final<<<3072, 256, 0, stream>>>(hist0 + (size_t)2*BH, hist1 + (size_t)2*BH,
                                    outsbF + (size_t)99*BH, cst, out);
}

// Round 9
// 2474.595 us; speedup vs baseline: 10.8977x; 1.1146x over previous
//
#include <hip/hip_runtime.h>

// ConditionalSmilesRnn: 3-layer LSTM, B=256, H=1024, steps=99, V=47, P=3.
// R9: single merged dispatch stream. Diag blocks (384) run the W_hh h-GEMMs
// (L2-resident, skew {0,3,6}) + fused cells; 256 extra blocks per dispatch run
// the W_ih x-GEMMs for a 2-step window (xp1 on even d, xp2 on odd d), fully
// overlapped. 105 dispatches total, no separate k_xp launches.

typedef unsigned short u16;
typedef __bf16 bf16x8 __attribute__((ext_vector_type(8)));
typedef float f32x4 __attribute__((ext_vector_type(4)));
typedef u16 u16x8 __attribute__((ext_vector_type(8)));

#define MFMA16(a,b,c) __builtin_amdgcn_mfma_f32_16x16x32_bf16((a),(b),(c),0,0,0)
#define BH 262144

__device__ __forceinline__ u16 f2bf(float f){
  unsigned u = __builtin_bit_cast(unsigned, f);
  u += 0x7fffu + ((u >> 16) & 1u);          // RN-even
  return (u16)(u >> 16);
}
__device__ __forceinline__ float bf2f(u16 s){
  unsigned u = ((unsigned)s) << 16;
  return __builtin_bit_cast(float, u);
}
__device__ __forceinline__ float sigm(float x){ return 1.f/(1.f+__expf(-x)); }
__device__ __forceinline__ float tanhfast(float x){ return 1.f - 2.f/(__expf(2.f*x)+1.f); }

__device__ __forceinline__ void ld_lds16(const u16* g, u16* l){
  __builtin_amdgcn_global_load_lds((const __attribute__((address_space(1))) void*)g,
                                   (__attribute__((address_space(3))) void*)l, 16, 0, 0);
}

// ---- f32 -> bf16 strided converter
__global__ void k_conv(const float* __restrict__ src, u16* __restrict__ dst,
                       long total, int srow, int sstride, int dstride, int doff){
  long i = ((long)blockIdx.x*blockDim.x + threadIdx.x)*8;
  if (i >= total) return;
  long r = i / srow;
  int  k = (int)(i - r*srow);
  const float* s = src + r*(long)sstride + k;
  u16x8 o;
  #pragma unroll
  for (int j=0;j<8;++j) o[j] = f2bf(s[j]);
  *(u16x8*)(dst + r*(long)dstride + doff + k) = o;
}

// ---- weight repack into per-(jt) contiguous stream blocks (K=1024, nkt=16).
// granule p = (jt*16 + kt)*512 + r*8 + s; src row n = (r>>4)*1024 + jt*16 + (r&15);
// cols kk = kt*64 + ((s ^ (r&7))<<3)  (LDS swizzle baked in).
__global__ void k_repackB(const float* __restrict__ Wih, const float* __restrict__ Whh,
                          u16* __restrict__ dst, int nkt){
  long p = (long)blockIdx.x*256 + threadIdx.x;
  int G = (int)(p & 511);
  long q = p >> 9;
  int kt = (int)(q % nkt);
  int jt = (int)(q / nkt);
  int r = G >> 3, s = G & 7;
  int kk = kt*64 + ((s ^ (r & 7)) << 3);
  int n = (r >> 4)*1024 + jt*16 + (r & 15);
  const float* src = (kk < 1024) ? Wih + (size_t)n*1024 + kk
                                 : Whh + (size_t)n*1024 + (kk - 1024);
  u16x8 o;
  #pragma unroll
  for (int j=0;j<8;++j) o[j] = f2bf(src[j]);
  *(u16x8*)(dst + p*8) = o;
}

// ---- misc prep: biases, pad-row zeroing, state init (hist rings), gx_prop
__global__ void k_misc(const float* __restrict__ b_ih0, const float* __restrict__ b_hh0,
                       const float* __restrict__ b_ihr, const float* __restrict__ b_hhr,
                       const float* __restrict__ h0, const float* __restrict__ c0,
                       const float* __restrict__ props, const float* __restrict__ W_ih0,
                       u16* __restrict__ Ebf, u16* __restrict__ Wdec,
                       float* __restrict__ bias0, float* __restrict__ bcat,
                       u16* __restrict__ hist0, u16* __restrict__ hist1,
                       u16* __restrict__ outsbF,
                       float* __restrict__ cst, float* __restrict__ gxp){
  long i = (long)blockIdx.x*256 + threadIdx.x;
  if (i < 4096){ bias0[i] = b_ih0[i] + b_hh0[i]; return; }
  i -= 4096;
  if (i < 2*4096){ bcat[i] = b_ihr[i] + b_hhr[i]; return; }
  i -= 2*4096;
  if (i < 1024){ Ebf[47*1024 + i] = 0; Wdec[47*1024 + i] = 0; return; }
  i -= 1024;
  if (i < (long)3*BH){
    int l = (int)(i >> 18); long r = i & (BH-1);
    u16 v = f2bf(h0[i]);
    if (l==0)      hist0[(size_t)7*BH + r] = v;
    else if (l==1) hist1[(size_t)7*BH + r] = v;
    else           outsbF[r] = v;
    cst[i] = c0[i];
    return;
  }
  i -= (long)3*BH;
  if (i < (long)256*4096){
    int b = (int)(i >> 12), n = (int)(i & 4095);
    const float* wr = W_ih0 + (long)n*1027 + 1024;
    gxp[i] = props[b*3+0]*wr[0] + props[b*3+1]*wr[1] + props[b*3+2]*wr[2];
  }
}

// ---- gx_emb[v][n] = sum_k E[v][k] * W_ih0[n][k]  (M=48 padded, N=4096, K=1024)
__global__ __launch_bounds__(64)
void k_gxemb(const u16* __restrict__ Ebf, const u16* __restrict__ Wih0b, float* __restrict__ gxe){
  const int lane = threadIdx.x;
  const int cl = lane & 15, ko = (lane >> 4)*8;
  const int m0 = blockIdx.x*16;
  const int n0 = blockIdx.y*16;
  f32x4 acc = {0.f,0.f,0.f,0.f};
  const u16* ap = Ebf   + (size_t)(m0+cl)*1024 + ko;
  const u16* bp = Wih0b + (size_t)(n0+cl)*1024 + ko;
  for (int k0=0; k0<1024; k0+=32){
    bf16x8 a = *(const bf16x8*)(ap + k0);
    bf16x8 b = *(const bf16x8*)(bp + k0);
    acc = MFMA16(a, b, acc);
  }
  const int rbase = (lane >> 4)*4;
  #pragma unroll
  for (int q=0;q<4;++q){
    int v = m0 + rbase + q;
    if (v < 47) gxe[(size_t)v*4096 + n0 + cl] = acc[q];
  }
}

// ================= shared K-loop (TM=128 x TN=64, K=1024, NT=16) =================
// 3 LDS slots x 24KB (pointer arithmetic only), 2-deep prefetch, one barrier
// per chunk, counted vmcnt, setprio around compute.
#define KLOOP_BODY(APTR_EXPR)                                                   \
  auto stage = [&](int s, int kt){                                              \
    const int kbase = kt*64;                                                    \
    u16* sA = lds + (size_t)s*12288;                                            \
    u16* sB = sA + 8192;                                                        \
    _Pragma("unroll")                                                           \
    for (int j=0;j<4;++j){                                                      \
      int G = j*256 + tid; int r = G >> 3;                                      \
      int kk = kbase + (((G & 7) ^ (r & 7)) << 3);                              \
      ld_lds16(APTR_EXPR, sA + (size_t)G*8);                                    \
    }                                                                           \
    _Pragma("unroll")                                                           \
    for (int j=0;j<2;++j){                                                      \
      int G = j*256 + tid;                                                      \
      ld_lds16(Bblk + (size_t)kt*4096 + (size_t)G*8, sB + (size_t)G*8);         \
    }                                                                           \
  };                                                                            \
  f32x4 acc[2][4];                                                              \
  _Pragma("unroll")                                                             \
  for (int mf=0; mf<2; ++mf)                                                    \
    _Pragma("unroll")                                                           \
    for (int g=0; g<4; ++g) acc[mf][g] = (f32x4){0.f,0.f,0.f,0.f};              \
  stage(0,0); stage(1,1);                                                       \
  for (int kt=0; kt<16; ++kt){                                                  \
    if (kt == 15) asm volatile("s_waitcnt vmcnt(0)" ::: "memory");              \
    else          asm volatile("s_waitcnt vmcnt(6)" ::: "memory");              \
    __builtin_amdgcn_s_barrier();                                               \
    asm volatile("" ::: "memory");                                              \
    if (kt+2 < 16) stage((kt+2)%3, kt+2);                                       \
    const u16* A = lds + (size_t)(kt%3)*12288;                                  \
    const u16* B = A + 8192;                                                    \
    __builtin_amdgcn_s_setprio(1);                                              \
    _Pragma("unroll")                                                           \
    for (int half=0; half<2; ++half){                                           \
      const int kg = half*4 + hi;                                               \
      bf16x8 a0, a1, b[4];                                                      \
      { int r = m0w + cl;      a0 = *(const bf16x8*)(A + r*64 + ((kg ^ (r&7))<<3)); } \
      { int r = m0w + 16 + cl; a1 = *(const bf16x8*)(A + r*64 + ((kg ^ (r&7))<<3)); } \
      _Pragma("unroll")                                                         \
      for (int g=0; g<4; ++g){                                                  \
        int r = g*16 + cl;                                                      \
        b[g] = *(const bf16x8*)(B + r*64 + ((kg ^ (r&7))<<3));                  \
      }                                                                         \
      _Pragma("unroll")                                                         \
      for (int g=0; g<4; ++g){                                                  \
        acc[0][g] = MFMA16(a0, b[g], acc[0][g]);                                \
        acc[1][g] = MFMA16(a1, b[g], acc[1][g]);                                \
      }                                                                         \
    }                                                                           \
    __builtin_amdgcn_s_setprio(0);                                              \
    asm volatile("" ::: "memory");                                              \
  }

// ---- diag tile: gates = W_hh . h_prev (+ gxe/gxp or xpart) + bias; fused cell.
template<int LAYER>
__device__ __forceinline__ void diagh_tile(int mt, int jt, int t,
    const int* __restrict__ x, const u16* hp, u16* aux, float* cc,
    const u16* __restrict__ Bblk, const float* __restrict__ bias,
    const float* __restrict__ gxe, const float* __restrict__ gxp,
    const u16* xpt, u16* lds)
{
  const int tid = threadIdx.x;
  const int lane = tid & 63, w = tid >> 6;
  const int cl = lane & 15, hi = lane >> 4;
  const int m_base = mt*128, m0w = w*32;

  KLOOP_BODY(hp + (size_t)(m_base + r)*1024 + kk)

  // fused LSTM cell. C/D: col = cl (-> hcol), row = hi*4+q (-> batch)
  const int hcol = jt*16 + cl;
  const float bi_ = bias[hcol], bf_ = bias[1024+hcol],
              bg_ = bias[2048+hcol], bo_ = bias[3072+hcol];
  #pragma unroll
  for (int mf=0; mf<2; ++mf){
    #pragma unroll
    for (int q=0; q<4; ++q){
      const int row = m_base + m0w + mf*16 + hi*4 + q;
      float gi = acc[mf][0][q] + bi_;
      float gf = acc[mf][1][q] + bf_;
      float gg = acc[mf][2][q] + bg_;
      float go = acc[mf][3][q] + bo_;
      if (LAYER == 0){
        const int tok = (t==0) ? 1 : x[row*100 + t];
        const float* ge = gxe + (size_t)tok*4096;
        const float* gp = gxp + (size_t)row*4096;
        gi += ge[hcol]        + gp[hcol];
        gf += ge[1024 + hcol] + gp[1024 + hcol];
        gg += ge[2048 + hcol] + gp[2048 + hcol];
        go += ge[3072 + hcol] + gp[3072 + hcol];
      } else {
        const u16* xr = xpt + (size_t)row*4096;
        gi += bf2f(xr[hcol]);
        gf += bf2f(xr[1024 + hcol]);
        gg += bf2f(xr[2048 + hcol]);
        go += bf2f(xr[3072 + hcol]);
      }
      const float i_ = sigm(gi), f_ = sigm(gf), o_ = sigm(go), g_ = tanhfast(gg);
      const size_t off = (size_t)row*1024 + hcol;
      const float cn = f_*cc[off] + i_*g_;
      cc[off] = cn;
      aux[off] = f2bf(o_*tanhfast(cn));
    }
  }
}

// ---- xp tile: xpart rows [m_base, m_base+128) of one step t -> bf16
__device__ __forceinline__ void xp_tile(int m_base, int jt,
    const u16* hp, const u16* __restrict__ Bblk, u16* xpo, u16* lds)
{
  const int tid = threadIdx.x;
  const int lane = tid & 63, w = tid >> 6;
  const int cl = lane & 15, hi = lane >> 4;
  const int m0w = w*32;

  KLOOP_BODY(hp + (size_t)(m_base + r)*1024 + kk)

  const int hcol = jt*16 + cl;
  #pragma unroll
  for (int mf=0; mf<2; ++mf){
    #pragma unroll
    for (int q=0; q<4; ++q){
      const int m = m_base + m0w + mf*16 + hi*4 + q;
      u16* xr = xpo + (size_t)m*4096 + hcol;
      xr[0]    = f2bf(acc[mf][0][q]);
      xr[1024] = f2bf(acc[mf][1][q]);
      xr[2048] = f2bf(acc[mf][2][q]);
      xr[3072] = f2bf(acc[mf][3][q]);
    }
  }
}

// ---- merged dispatch: blocks [0,384) = diag (L0@d, L1@d-3, L2@d-6);
// blocks [384,640) = xp window (even d: xp1 w=(d-2)/2; odd d: xp2 w=(d-5)/2).
__global__ __launch_bounds__(256)
void k_diag(int d, const int* __restrict__ x, u16* hist0, u16* hist1, u16* outsbF,
            float* __restrict__ cst, const u16* __restrict__ WpkH,
            const u16* __restrict__ WpkI,
            const float* __restrict__ bias0, const float* __restrict__ bcat,
            const float* __restrict__ gxe, const float* __restrict__ gxp,
            u16* __restrict__ xpb1, u16* __restrict__ xpb2)
{
  extern __shared__ u16 lds[];
  const int id = blockIdx.x;
  if (id < 384){
    const int mt = id / 192;
    const int slot = id - mt*192;
    const int layer = slot >> 6;
    const int jt = slot & 63;
    const int t = d - 3*layer;
    if (t < 0 || t > 98) return;
    if (layer == 0){
      diagh_tile<0>(mt, jt, t, x, hist0 + (size_t)((t+7)&7)*BH, hist0 + (size_t)(t&7)*BH,
                    cst, WpkH + (size_t)jt*65536, bias0, gxe, gxp, nullptr, lds);
    } else if (layer == 1){
      const u16* xpt = xpb1 + (size_t)((((t>>1)&1)<<1) + (t&1))*1048576;
      diagh_tile<1>(mt, jt, t, x, hist1 + (size_t)((t+7)&7)*BH, hist1 + (size_t)(t&7)*BH,
                    cst + BH, WpkH + (size_t)4194304 + (size_t)jt*65536, bcat,
                    nullptr, nullptr, xpt, lds);
    } else {
      const u16* xpt = xpb2 + (size_t)((((t>>1)&1)<<1) + (t&1))*1048576;
      diagh_tile<2>(mt, jt, t, x, outsbF + (size_t)t*BH, outsbF + (size_t)(t+1)*BH,
                    cst + 2*BH, WpkH + (size_t)8388608 + (size_t)jt*65536, bcat + 4096,
                    nullptr, nullptr, xpt, lds);
    }
  } else {
    const int idx = id - 384;
    const int mtx = idx >> 6, jt = idx & 63;
    const int tsub = mtx >> 1, m_base = (mtx & 1)*128;
    int w; const u16* hist; const u16* Wblk; u16* xpo;
    if ((d & 1) == 0){ w = (d-2)>>1; hist = hist0; Wblk = WpkI;                     xpo = xpb1; }
    else             { w = (d-5)>>1; hist = hist1; Wblk = WpkI + (size_t)4194304;   xpo = xpb2; }
    const int t = 2*w + tsub;
    if (t > 98) return;
    xp_tile(m_base, jt, hist + (size_t)(t&7)*BH, Wblk + (size_t)jt*65536,
            xpo + (size_t)(((w&1)<<1) + tsub)*1048576, lds);
  }
}

// ---- decoder: logits[b,t,v] = outs[t,b,:] . Wdec[v,:] + b_dec[v]
__global__ __launch_bounds__(256)
void k_decode(const u16* __restrict__ outs, const u16* __restrict__ Wdec,
              const float* __restrict__ bdec, float* __restrict__ logits){
  const int lane = threadIdx.x & 63, w = threadIdx.x >> 6;
  const int cl = lane & 15, ko = (lane >> 4)*8;
  const size_t m0 = ((size_t)blockIdx.x*4 + w)*16;
  const u16* ap = outs + (m0+cl)*1024 + ko;
  f32x4 acc[3];
  #pragma unroll
  for (int nt=0; nt<3; ++nt) acc[nt] = (f32x4){0.f,0.f,0.f,0.f};
  const u16* bp = Wdec + (size_t)cl*1024 + ko;
  for (int k0=0; k0<1024; k0+=32){
    bf16x8 a = *(const bf16x8*)(ap + k0);
    #pragma unroll
    for (int nt=0; nt<3; ++nt){
      bf16x8 b = *(const bf16x8*)(bp + (size_t)nt*16*1024 + k0);
      acc[nt] = MFMA16(a, b, acc[nt]);
    }
  }
  const int rbase = (lane >> 4)*4;
  #pragma unroll
  for (int nt=0; nt<3; ++nt){
    #pragma unroll
    for (int q=0; q<4; ++q){
      int v = nt*16 + cl;
      if (v < 47){
        size_t row = m0 + rbase + q;   // row = t*256 + b
        int tt = (int)(row >> 8);
        int b  = (int)(row & 255);
        logits[((size_t)b*99 + tt)*47 + v] = acc[nt][q] + bdec[v];
      }
    }
  }
}

// ---- final hT / cT copy-out (t=98: hist slots 98&7=2, outsbF slot 99)
__global__ void k_final(const u16* __restrict__ h0s, const u16* __restrict__ h1s,
                        const u16* __restrict__ h2s, const float* __restrict__ cst,
                        float* __restrict__ out){
  long i = (long)blockIdx.x*256 + threadIdx.x;
  if (i < (long)3*BH){
    int l = (int)(i >> 18); long r = i & (BH-1);
    const u16* src = (l==0) ? h0s : (l==1) ? h1s : h2s;
    out[1191168 + i] = bf2f(src[r]);
    out[1191168 + 786432 + i] = cst[i];
  }
}

extern "C" void kernel_launch(void* const* d_in, const int* in_sizes, int n_in,
                              void* d_out, int out_size, void* d_ws, size_t ws_size,
                              hipStream_t stream) {
  (void)in_sizes; (void)n_in; (void)out_size; (void)ws_size;
  const int*   x      = (const int*)  d_in[0];
  const float* props  = (const float*)d_in[1];
  const float* h0     = (const float*)d_in[2];
  const float* c0     = (const float*)d_in[3];
  const float* E      = (const float*)d_in[4];
  const float* W_ih0  = (const float*)d_in[5];
  const float* W_hh0  = (const float*)d_in[6];
  const float* b_ih0  = (const float*)d_in[7];
  const float* b_hh0  = (const float*)d_in[8];
  const float* W_ih_r = (const float*)d_in[9];
  const float* W_hh_r = (const float*)d_in[10];
  const float* b_ih_r = (const float*)d_in[11];
  const float* b_hh_r = (const float*)d_in[12];
  const float* W_dec  = (const float*)d_in[13];
  const float* b_dec  = (const float*)d_in[14];
  float* out = (float*)d_out;

  // workspace layout (~130 MB)
  u16* WpkH   = (u16*)d_ws;                 // 3 x 4,194,304 (W_hh stream blocks)
  u16* WpkI   = WpkH  + (size_t)12582912;   // 2 x 4,194,304 (W_ih_r stream blocks)
  u16* Wdec   = WpkI  + (size_t)8388608;    // 48*1024 (row 47 = 0)
  u16* Ebf    = Wdec  + (size_t)49152;      // 48*1024 (row 47 = 0)
  u16* hist0  = Ebf   + (size_t)49152;      // 8 x BH  (h0 ring; slot 7 = init)
  u16* hist1  = hist0 + (size_t)8*BH;       // 8 x BH
  u16* outsbF = hist1 + (size_t)8*BH;       // 100 x BH (slot 0 = h2 init; t -> t+1)
  u16* xpb1   = outsbF + (size_t)100*BH;    // [2 win-parity][2 tsub][256][4096]
  u16* xpb2   = xpb1  + (size_t)4194304;    // same
  u16* Wih0b  = xpb1;                       // ALIAS: prep-only, dead before xp writes
  float* gxe   = (float*)(xpb2 + (size_t)4194304); // 48*4096
  float* gxp   = gxe   + (size_t)196608;           // 256*4096
  float* bias0 = gxp   + (size_t)1048576;          // 4096
  float* bcat  = bias0 + 4096;                     // 2*4096
  float* cst   = bcat  + 8192;                     // 3 x BH f32

  // ---- prep
  k_repackB<<<2048, 256, 0, stream>>>(W_hh0, W_hh0, WpkH, 16);
  k_repackB<<<2048, 256, 0, stream>>>(W_hh_r, W_hh_r, WpkH + (size_t)4194304, 16);
  k_repackB<<<2048, 256, 0, stream>>>(W_hh_r + (size_t)4194304, W_hh_r + (size_t)4194304,
                                      WpkH + (size_t)8388608, 16);
  k_repackB<<<2048, 256, 0, stream>>>(W_ih_r, W_ih_r, WpkI, 16);
  k_repackB<<<2048, 256, 0, stream>>>(W_ih_r + (size_t)4194304, W_ih_r + (size_t)4194304,
                                      WpkI + (size_t)4194304, 16);
  k_conv<<<2048, 256, 0, stream>>>(W_ih0, Wih0b, (long)4096*1024, 1024, 1027, 1024, 0);
  k_conv<<<24,   256, 0, stream>>>(E,     Ebf,   (long)47*1024,   1024, 1024, 1024, 0);
  k_conv<<<24,   256, 0, stream>>>(W_dec, Wdec,  (long)47*1024,   1024, 1024, 1024, 0);
  k_misc<<<7221, 256, 0, stream>>>(b_ih0, b_hh0, b_ih_r, b_hh_r, h0, c0, props, W_ih0,
                                   Ebf, Wdec, bias0, bcat, hist0, hist1, outsbF, cst, gxp);
  k_gxemb<<<dim3(3,256), 64, 0, stream>>>(Ebf, Wih0b, gxe);

  // ---- merged recurrence: d runs (L0@d, L1@d-3, L2@d-6) + one xp window
  (void)hipFuncSetAttribute(reinterpret_cast<const void*>(k_diag),
                            hipFuncAttributeMaxDynamicSharedMemorySize, 73728);
  for (int d = 0; d <= 104; ++d){
    bool hx = ((d & 1) == 0) ? (d >= 2 && d <= 100) : (d >= 5 && d <= 103);
    k_diag<<<384 + (hx ? 256 : 0), 256, 73728, stream>>>(
        d, x, hist0, hist1, outsbF, cst, WpkH, WpkI,
        bias0, bcat, gxe, gxp, xpb1, xpb2);
  }

  // ---- decode + final states
  k_decode<<<396, 256, 0, stream>>>(outsbF + (size_t)BH, Wdec, b_dec, out);
  k_final<<<3072, 256, 0, stream>>>(hist0 + (size_t)2*BH, hist1 + (size_t)2*BH,
                                    outsbF + (size_t)99*BH, cst, out);
}